// Round 6
// baseline (547.926 us; speedup 1.0000x reference)
//
#include <hip/hip_runtime.h>
#include <math.h>

#define LSEQ 4096
#define NFFT 4096      // complex FFT length (real length 8192 via packing)
#define NM   64
#define NBH  4096

__device__ __forceinline__ float2 cmulf(float2 a, float2 b) {
  return make_float2(a.x*b.x - a.y*b.y, a.x*b.y + a.y*b.x);
}
// a * conj(b)
__device__ __forceinline__ float2 cmulc(float2 a, float2 b) {
  return make_float2(a.x*b.x + a.y*b.y, a.y*b.x - a.x*b.y);
}
__device__ __forceinline__ float2 caddf(float2 a, float2 b){ return make_float2(a.x+b.x, a.y+b.y); }
__device__ __forceinline__ float2 csubf(float2 a, float2 b){ return make_float2(a.x-b.x, a.y-b.y); }

// base-4 digit swap of a 4-bit value: reg r holds freq digit RHO(r) after fused r16
__host__ __device__ constexpr int RHO(int d){ return ((d&3)<<2) | (d>>2); }

// storage swizzle: phys[3:0]^=l[7:4], phys[7:4]^=l[11:8] -> all 5 passes at b64 bank floor
__device__ __forceinline__ int ZS(int i){ return i ^ ((i>>4)&15) ^ (((i>>8)&15)<<4); }

// ---- radix-4 butterflies (validated r1..r5 lineage) ----
__device__ __forceinline__ void r4_fwd(float2& x0, float2& x1, float2& x2, float2& x3,
                                       float2 w1, float2 w2, float2 w3) {
  float2 A = caddf(x0,x2), C = csubf(x0,x2);
  float2 B = caddf(x1,x3), D = csubf(x1,x3);
  float2 y1 = make_float2(C.x + D.y, C.y - D.x);   // C - iD
  float2 y3 = make_float2(C.x - D.y, C.y + D.x);   // C + iD
  x0 = caddf(A,B);
  x1 = cmulf(y1,w1);
  x2 = cmulf(csubf(A,B),w2);
  x3 = cmulf(y3,w3);
}
// inverse butterfly taking FORWARD twiddles (conj applied inside, free)
__device__ __forceinline__ void r4_invc(float2& y0, float2& y1, float2& y2, float2& y3,
                                        float2 w1, float2 w2, float2 w3) {
  float2 c1 = cmulc(y1,w1);
  float2 c2 = cmulc(y2,w2);
  float2 c3 = cmulc(y3,w3);
  float2 ap = caddf(y0,c2), bp = csubf(y0,c2);
  float2 cp = caddf(c1,c3);
  float2 dp = make_float2(c3.y - c1.y, c1.x - c3.x);  // i*(c1-c3)
  y0 = caddf(ap,cp); y1 = caddf(bp,dp); y2 = csubf(ap,cp); y3 = csubf(bp,dp);
}

#define DECL_CONSTS \
  const float C16R[4]={1.f,0.9238795325112867f,0.7071067811865476f,0.3826834323650898f}; \
  const float C16I[4]={0.f,-0.3826834323650898f,-0.7071067811865476f,-0.9238795325112867f}; \
  const float C8R[4] ={1.f,0.7071067811865476f,0.f,-0.7071067811865476f}; \
  const float C8I[4] ={0.f,-0.7071067811865476f,-1.f,-0.7071067811865476f}; \
  const float C163R[4]={1.f,0.3826834323650898f,-0.7071067811865476f,-0.9238795325112867f}; \
  const float C163I[4]={0.f,-0.9238795325112867f,-0.7071067811865476f,0.3826834323650898f};

__device__ __forceinline__ void r16_fwd1(float2 x[16]) {
  DECL_CONSTS
  #pragma unroll
  for (int k0 = 0; k0 < 4; k0++)
    r4_fwd(x[k0], x[k0+4], x[k0+8], x[k0+12],
           make_float2(C16R[k0],C16I[k0]), make_float2(C8R[k0],C8I[k0]),
           make_float2(C163R[k0],C163I[k0]));
  #pragma unroll
  for (int q = 0; q < 4; q++)
    r4_fwd(x[4*q], x[4*q+1], x[4*q+2], x[4*q+3],
           make_float2(1.f,0.f), make_float2(1.f,0.f), make_float2(1.f,0.f));
}
__device__ __forceinline__ void r16_inv1(float2 x[16]) {
  DECL_CONSTS
  #pragma unroll
  for (int q = 0; q < 4; q++)
    r4_invc(x[4*q], x[4*q+1], x[4*q+2], x[4*q+3],
            make_float2(1.f,0.f), make_float2(1.f,0.f), make_float2(1.f,0.f));
  #pragma unroll
  for (int k0 = 0; k0 < 4; k0++)
    r4_invc(x[k0], x[k0+4], x[k0+8], x[k0+12],
            make_float2(C16R[k0],C16I[k0]), make_float2(C8R[k0],C8I[k0]),
            make_float2(C163R[k0],C163I[k0]));
}
// table packs: w[0..3]=w1[k0], [4..7]=w2[k0], [8..11]=w3[k0], [12..14]=wB,wB2,wB3
__device__ __forceinline__ void r16_fwd_t(float2 x[16], const float4 tp[8]) {
  float2 tw[16];
  #pragma unroll
  for (int q = 0; q < 8; q++) {
    tw[2*q]   = make_float2(tp[q].x, tp[q].y);
    tw[2*q+1] = make_float2(tp[q].z, tp[q].w);
  }
  #pragma unroll
  for (int k0 = 0; k0 < 4; k0++)
    r4_fwd(x[k0], x[k0+4], x[k0+8], x[k0+12], tw[k0], tw[4+k0], tw[8+k0]);
  #pragma unroll
  for (int q = 0; q < 4; q++)
    r4_fwd(x[4*q], x[4*q+1], x[4*q+2], x[4*q+3], tw[12], tw[13], tw[14]);
}
__device__ __forceinline__ void r16_inv_t(float2 x[16], const float4 tp[8]) {
  float2 tw[16];
  #pragma unroll
  for (int q = 0; q < 8; q++) {
    tw[2*q]   = make_float2(tp[q].x, tp[q].y);
    tw[2*q+1] = make_float2(tp[q].z, tp[q].w);
  }
  #pragma unroll
  for (int q = 0; q < 4; q++)
    r4_invc(x[4*q], x[4*q+1], x[4*q+2], x[4*q+3], tw[12], tw[13], tw[14]);
  #pragma unroll
  for (int k0 = 0; k0 < 4; k0++)
    r4_invc(x[k0], x[k0+4], x[k0+8], x[k0+12], tw[k0], tw[4+k0], tw[8+k0]);
}

// ---------------- prep: twiddle-pack tables, one entry per thread ----------------
__device__ __forceinline__ double slotExpo(int s, int t) {   // 1/4096 units
  if (s < 4)  return (double)(t + 256*s);
  if (s < 8)  return (double)(2*t + 512*(s-4));
  if (s < 12) return (double)(3*t + 768*(s-8));
  if (s == 12) return (double)(4*t);
  if (s == 13) return (double)(8*t);
  if (s == 14) return (double)(12*t);
  return 0.0;
}
__device__ __forceinline__ float2 E4096(double e) {
  double ang = -2.0*M_PI*e/4096.0;
  return make_float2((float)cos(ang), (float)sin(ang));
}
__global__ void tables_kernel(float4* __restrict__ tp1, float4* __restrict__ tp2,
                              float2* __restrict__ wp3) {
  int idx = blockIdx.x*blockDim.x + threadIdx.x;
  if (idx < 2048) {                       // tp1[q*256+t], wA = W4096^t
    int q = idx >> 8, t = idx & 255;
    float2 wa = E4096(slotExpo(2*q,   t));
    float2 wb = E4096(slotExpo(2*q+1, t));
    tp1[q*256 + t] = make_float4(wa.x, wa.y, wb.x, wb.y);
  } else if (idx < 2176) {                // tp2[q*16+j], wA = W256^j = W4096^{16j}
    int r = idx - 2048; int q = r >> 4, j = r & 15;
    float2 wa = E4096(slotExpo(2*q,   16*j));
    float2 wb = E4096(slotExpo(2*q+1, 16*j));
    tp2[q*16 + j] = make_float4(wa.x, wa.y, wb.x, wb.y);
  } else if (idx < 2432) {                // wp3[b] = W8192^{RHO(b>>4)+16*RHO(b&15)}
    int b = idx - 2176;
    int e = RHO(b>>4) + 16*RHO(b&15);
    double ang = -2.0*M_PI*(double)e/8192.0;
    wp3[b] = make_float2((float)cos(ang), (float)sin(ang));
  }
}

// ---------------- prep: at_roots via 4 Cauchy dots (fp64) -- unchanged ----------------
__global__ void cauchy_kernel(const float* __restrict__ Lre, const float* __restrict__ Lim,
                              const float* __restrict__ Pre, const float* __restrict__ Pim,
                              const float* __restrict__ Bre, const float* __restrict__ Bim,
                              const float* __restrict__ Cri, const float* __restrict__ lstep,
                              float2* __restrict__ a_out) {
  int k = blockIdx.x*blockDim.x + threadIdx.x;
  if (k >= LSEQ) return;
  double step = exp((double)lstep[0]);
  double ang = -2.0*M_PI*(double)k/(double)LSEQ;
  double wr = cos(ang), wi = sin(ang);
  double nr = 1.0 - wr, ni = -wi;
  double dr = 1.0 + wr, di = wi;
  double dn = dr*dr + di*di;
  double gre = (2.0/step) * (nr*dr + ni*di)/dn;
  double gim = (2.0/step) * (ni*dr - nr*di)/dn;
  double cre = 2.0*dr/dn, cim = -2.0*di/dn;
  double k00r=0,k00i=0,k01r=0,k01i=0,k10r=0,k10i=0,k11r=0,k11i=0;
  for (int n = 0; n < NM; n++) {
    double lre = Lre[n], lim = Lim[n];
    double pre = Pre[n], pim = Pim[n];
    double bre = Bre[n], bim = Bim[n];
    double ccr = Cri[2*n], cci = Cri[2*n+1];
    double er = gre - lre, ei = gim - lim;
    double inv = 1.0/(er*er + ei*ei);
    double ir =  er*inv, ii = -ei*inv;
    double v00r = ccr*bre + cci*bim, v00i = ccr*bim - cci*bre;
    double v01r = ccr*pre + cci*pim, v01i = ccr*pim - cci*pre;
    double v10r = pre*bre + pim*bim, v10i = pre*bim - pim*bre;
    double v11r = pre*pre + pim*pim, v11i = 0.0;
    k00r += v00r*ir - v00i*ii;  k00i += v00r*ii + v00i*ir;
    k01r += v01r*ir - v01i*ii;  k01i += v01r*ii + v01i*ir;
    k10r += v10r*ir - v10i*ii;  k10i += v10r*ii + v10i*ir;
    k11r += v11r*ir - v11i*ii;  k11i += v11r*ii + v11i*ir;
  }
  double numr = k01r*k10r - k01i*k10i, numi = k01r*k10i + k01i*k10r;
  double der = 1.0 + k11r, dei = k11i;
  double dinv = 1.0/(der*der + dei*dei);
  double qr = (numr*der + numi*dei)*dinv;
  double qi = (numi*der - numr*dei)*dinv;
  double tr = k00r - qr, ti = k00i - qi;
  double ar = cre*tr - cim*ti, ai = cre*ti + cim*tr;
  a_out[k] = make_float2((float)ar, (float)ai);
}

// ---------------- prep: K[l] = Re(IDFT_L(a))[l], 64 lanes per output ----------------
__global__ void ktime_kernel(const float2* __restrict__ a, float* __restrict__ K) {
  int lane = threadIdx.x & 63;
  int l = blockIdx.x * (blockDim.x >> 6) + (threadIdx.x >> 6);
  if (l >= LSEQ) return;
  double ang0 = 2.0*M_PI*(double)((l*lane) & (LSEQ-1))/(double)LSEQ;
  double tr = cos(ang0), ti = sin(ang0);
  double ang1 = 2.0*M_PI*(double)(l & 63)/64.0;
  double wr = cos(ang1), wi = sin(ang1);
  double acc = 0.0;
  for (int k = 0; k < 64; k++) {
    float2 ak = a[lane + (k << 6)];
    acc += (double)ak.x*tr - (double)ak.y*ti;
    double ntr = tr*wr - ti*wi;
    ti = tr*wi + ti*wr;
    tr = ntr;
  }
  for (int off = 32; off > 0; off >>= 1) acc += __shfl_down(acc, off);
  if (lane == 0) K[l] = (float)(acc/(double)LSEQ);
}

// ---------------- prep: H[k] = sum_l K[l] W8192^{kl}, k=0..4096 (fp64 direct) ----------
__global__ void hspec_kernel(const float* __restrict__ K, float2* __restrict__ H) {
  int lane = threadIdx.x & 63;
  int k = blockIdx.x * (blockDim.x >> 6) + (threadIdx.x >> 6);
  if (k > NFFT) return;
  int m0 = (k*lane) & 8191;
  double a0 = -2.0*M_PI*(double)m0/8192.0;
  double cr = cos(a0), ci = sin(a0);
  int ms = (k << 6) & 8191;
  double as = -2.0*M_PI*(double)ms/8192.0;
  double sr = cos(as), si = sin(as);
  double accr = 0.0, acci = 0.0;
  for (int j = 0; j < 64; j++) {
    double Kv = (double)K[lane + (j << 6)];
    accr += Kv*cr; acci += Kv*ci;
    double nr2 = cr*sr - ci*si;
    ci = cr*si + ci*sr; cr = nr2;
  }
  for (int off = 32; off > 0; off >>= 1) {
    accr += __shfl_down(accr, off);
    acci += __shfl_down(acci, off);
  }
  if (lane == 0) H[k] = make_float2((float)accr, (float)acci);
}

// ---------------- prep: lay H out per (block,reg) with D folded and 1/16384 scale ------
__global__ void map_kernel(const float2* __restrict__ H, const float* __restrict__ Dp,
                           float2* __restrict__ KdA, float2* __restrict__ KdB) {
  int idx = blockIdx.x*blockDim.x + threadIdx.x;
  if (idx >= NFFT) return;
  int b = idx >> 4, c = idx & 15;
  int k = RHO(b>>4) + 16*RHO(b&15) + 256*RHO(c);
  const float s = 1.0f/16384.0f;
  float Dv = Dp[0];
  float2 ha = H[k], hb = H[NFFT - k];
  KdA[idx] = make_float2((ha.x + Dv)*s, ha.y*s);
  KdB[idx] = make_float2((hb.x + Dv)*s, hb.y*s);
}

// ---------------- main: 1 row/block, packed real-8192 FFT as complex-4096 ----------------
// 256 thr (4 waves), 32KB LDS -> 4 blocks/CU. 4 full barriers. P3 spectral step pairs
// freq k with 4096-k; thread->block map (nibble const) keeps partner blocks co-wave so
// P3 waves touch disjoint LDS (no internal sync needed).
__global__ __launch_bounds__(256, 4)
void conv_kernel(const float* __restrict__ u,
                 const float4* __restrict__ tp1, const float4* __restrict__ tp2,
                 const float2* __restrict__ wp3, const float2* __restrict__ KdA,
                 const float2* __restrict__ KdB, float* __restrict__ out) {
  __shared__ float2 z[NFFT];
  const int tid = threadIdx.x;
  const float2* u2 = (const float2*)(u + (size_t)blockIdx.x*LSEQ);
  float2 x[16];
  // ---- P1: load packed row, r16 fwd (stride 256) ----
  {
    float4 tpr[8];
    #pragma unroll
    for (int q = 0; q < 8; q++) tpr[q] = tp1[(q<<8) + tid];
    #pragma unroll
    for (int k = 0; k < 8; k++) x[k] = u2[tid + (k<<8)];
    #pragma unroll
    for (int k = 8; k < 16; k++) x[k] = make_float2(0.f, 0.f);
    r16_fwd_t(x, tpr);
    #pragma unroll
    for (int k = 0; k < 16; k++) z[ZS(tid + (k<<8))] = x[k];
  }
  __syncthreads();
  // ---- P2: r16 fwd (stride 16) ----
  const int j4 = tid & 15, gb = (tid>>4)<<8;
  {
    float4 tq[8];
    #pragma unroll
    for (int q = 0; q < 8; q++) tq[q] = tp2[(q<<4) + j4];
    #pragma unroll
    for (int k = 0; k < 16; k++) x[k] = z[ZS(gb + (k<<4) + j4)];
    r16_fwd_t(x, tq);
    #pragma unroll
    for (int k = 0; k < 16; k++) z[ZS(gb + (k<<4) + j4)] = x[k];
  }
  __syncthreads();
  // ---- P3: final r16 fwd + real-untangle x H + re-pack + r16 inv ----
  {
    // block assignment: group g handles high digit Hmap[g]; pairs co-wave
    int h16 = (int)((0xA9B8C7D6E5F42310ull >> ((tid>>4)<<2)) & 15);
    int b = (h16<<4) | j4;
    int pb;
    if (tid >= 16) pb = (RHO(16 - RHO(b>>4)) << 4) | (15 - j4);
    else           pb = (tid == 0) ? 0 : RHO(16 - RHO(tid));
    const int bb = b<<4, pbb = pb<<4;
    float2 px[16];
    #pragma unroll
    for (int c = 0; c < 16; c++) x[c] = z[ZS(bb + c)];
    #pragma unroll
    for (int c = 0; c < 16; c++) px[c] = z[ZS(pbb + c)];
    r16_fwd1(x);    // x[c]  = Z[k(b,c)],  k = RHO(b>>4)+16*RHO(b&15)+256*RHO(c)
    r16_fwd1(px);   // px[c] = Z[k(pb,c)]; mirror of x[c] is px[15-c] (thread0: M0T)
    const float2 wbase = wp3[b];
    const float4* KdA4 = (const float4*)(KdA + bb);
    const float4* KdB4 = (const float4*)(KdB + bb);
    // W32^{RHO(c)} = exp(-i*pi*RHO(c)/16)
    const float CW32R[16] = {1.f,0.7071067811865476f,0.f,-0.7071067811865476f,
                             0.9807852804032304f,0.5555702330196022f,-0.19509032201612825f,-0.8314696123025452f,
                             0.9238795325112867f,0.3826834323650898f,-0.3826834323650898f,-0.9238795325112867f,
                             0.8314696123025452f,0.19509032201612825f,-0.5555702330196022f,-0.9807852804032304f};
    const float CW32I[16] = {0.f,-0.7071067811865476f,-1.f,-0.7071067811865476f,
                             -0.19509032201612825f,-0.8314696123025452f,-0.9807852804032304f,-0.5555702330196022f,
                             -0.3826834323650898f,-0.9238795325112867f,-0.9238795325112867f,-0.3826834323650898f,
                             -0.5555702330196022f,-0.9807852804032304f,-0.8314696123025452f,-0.19509032201612825f};
    const int M0T[16] = {0,3,2,1,15,14,13,12,11,10,9,8,7,6,5,4};
    const bool t0 = (tid == 0);
    #pragma unroll
    for (int c2 = 0; c2 < 8; c2++) {
      float4 a4 = KdA4[c2], b4 = KdB4[c2];
      #pragma unroll
      for (int cc = 0; cc < 2; cc++) {
        const int c = 2*c2 + cc;
        float2 kda = cc ? make_float2(a4.z, a4.w) : make_float2(a4.x, a4.y);
        float2 kdb = cc ? make_float2(b4.z, b4.w) : make_float2(b4.x, b4.y);
        float2 Zo = x[c];
        float2 Zm = t0 ? px[M0T[c]] : px[15-c];
        float2 wk = cmulf(wbase, make_float2(CW32R[c], CW32I[c]));  // W8192^k
        float Sx = Zo.x + Zm.x, Sy = Zo.y - Zm.y;    // S = Zo + conj(Zm)
        float Dx = Zo.x - Zm.x, Dy = Zo.y + Zm.y;    // D = Zo - conj(Zm)
        float2 t1 = cmulf(wk, make_float2(Dx, Dy));
        float2 Up = make_float2(Sx + t1.y, Sy - t1.x);    // U'  = S - i*t1
        float2 Um = make_float2(Sx - t1.y, -Sy - t1.x);   // U'm = conj(S) - i*conj(t1)
        float2 Yp = cmulf(Up, kda);                        // ~ Y[k]
        float2 Ym = cmulf(Um, kdb);                        // ~ Y[N-k]
        float Pxx = Yp.x + Ym.x, Pyy = Yp.y - Ym.y;       // Y' + conj(Ym)
        float Qx  = Yp.x - Ym.x, Qy  = Yp.y + Ym.y;       // Y' - conj(Ym)
        float2 t2 = cmulc(make_float2(Qx, Qy), wk);        // Q * conj(wk)
        x[c] = make_float2(Pxx - t2.y, Pyy + t2.x);        // V = P + i*t2
      }
    }
    r16_inv1(x);
    #pragma unroll
    for (int c = 0; c < 16; c++) z[ZS(bb + c)] = x[c];
  }
  __syncthreads();
  // ---- P4: r16 inv (stride 16) ----
  {
    float4 tq[8];
    #pragma unroll
    for (int q = 0; q < 8; q++) tq[q] = tp2[(q<<4) + j4];
    #pragma unroll
    for (int k = 0; k < 16; k++) x[k] = z[ZS(gb + (k<<4) + j4)];
    r16_inv_t(x, tq);
    #pragma unroll
    for (int k = 0; k < 16; k++) z[ZS(gb + (k<<4) + j4)] = x[k];
  }
  __syncthreads();
  // ---- P5: r16 inv (stride 256), unpack v[n] = (y[2n], y[2n+1]) ----
  {
    float4 tpr[8];
    #pragma unroll
    for (int q = 0; q < 8; q++) tpr[q] = tp1[(q<<8) + tid];
    #pragma unroll
    for (int k = 0; k < 16; k++) x[k] = z[ZS(tid + (k<<8))];
    r16_inv_t(x, tpr);
    float2* o2 = (float2*)(out + (size_t)blockIdx.x*LSEQ);
    #pragma unroll
    for (int k = 0; k < 8; k++) o2[tid + (k<<8)] = x[k];
  }
}

extern "C" void kernel_launch(void* const* d_in, const int* in_sizes, int n_in,
                              void* d_out, int out_size, void* d_ws, size_t ws_size,
                              hipStream_t stream) {
  const float* u     = (const float*)d_in[0];
  const float* Lre   = (const float*)d_in[1];
  const float* Lim   = (const float*)d_in[2];
  const float* Pre   = (const float*)d_in[3];
  const float* Pim   = (const float*)d_in[4];
  const float* Bre   = (const float*)d_in[5];
  const float* Bim   = (const float*)d_in[6];
  const float* Cri   = (const float*)d_in[7];
  const float* Dp    = (const float*)d_in[8];
  const float* lstep = (const float*)d_in[9];
  float* out = (float*)d_out;

  char* ws = (char*)d_ws;
  float2* a_ws   = (float2*)(ws);             //  32768 B : at_roots
  float*  K_ws   = (float*)(ws + 32768);      //  16384 B : K time domain
  float4* tp1_ws = (float4*)(ws + 49152);     //  32768 B : P1/P5 packs [8][256]
  float4* tp2_ws = (float4*)(ws + 81920);     //   2048 B : P2/P4 packs [8][16]
  float2* wp3_ws = (float2*)(ws + 83968);     //   2048 B : per-block W8192 base
  float2* H_ws   = (float2*)(ws + 86016);     //  32776 B : half-spectrum H[0..4096]
  float2* KdA_ws = (float2*)(ws + 118800);    //  32768 B : H[k] per (block,reg)
  float2* KdB_ws = (float2*)(ws + 151568);    //  32768 B : H[N-k] per (block,reg)

  hipLaunchKernelGGL(tables_kernel, dim3(10),   dim3(256), 0, stream,
                     tp1_ws, tp2_ws, wp3_ws);
  hipLaunchKernelGGL(cauchy_kernel, dim3(64),   dim3(64),  0, stream,
                     Lre, Lim, Pre, Pim, Bre, Bim, Cri, lstep, a_ws);
  hipLaunchKernelGGL(ktime_kernel,  dim3(1024), dim3(256), 0, stream, a_ws, K_ws);
  hipLaunchKernelGGL(hspec_kernel,  dim3(1025), dim3(256), 0, stream, K_ws, H_ws);
  hipLaunchKernelGGL(map_kernel,    dim3(16),   dim3(256), 0, stream,
                     H_ws, Dp, KdA_ws, KdB_ws);
  hipLaunchKernelGGL(conv_kernel,   dim3(NBH),  dim3(256), 0, stream,
                     u, tp1_ws, tp2_ws, wp3_ws, KdA_ws, KdB_ws, out);
}

// Round 7
// 233.407 us; speedup vs baseline: 2.3475x; 2.3475x over previous
//
#include <hip/hip_runtime.h>
#include <math.h>

#define LSEQ 4096
#define NFFT 4096      // complex FFT length (real length 8192 via packing)
#define NM   64
#define NBH  4096

__device__ __forceinline__ float2 cmulf(float2 a, float2 b) {
  return make_float2(a.x*b.x - a.y*b.y, a.x*b.y + a.y*b.x);
}
// a * conj(b)
__device__ __forceinline__ float2 cmulc(float2 a, float2 b) {
  return make_float2(a.x*b.x + a.y*b.y, a.y*b.x - a.x*b.y);
}
__device__ __forceinline__ float2 caddf(float2 a, float2 b){ return make_float2(a.x+b.x, a.y+b.y); }
__device__ __forceinline__ float2 csubf(float2 a, float2 b){ return make_float2(a.x-b.x, a.y-b.y); }

// base-4 digit swap of a 4-bit value: reg r holds freq digit RHO(r) after fused r16
__host__ __device__ constexpr int RHO(int d){ return ((d&3)<<2) | (d>>2); }

// storage swizzle: phys[3:0]^=l[7:4], phys[7:4]^=l[11:8] -> all 5 passes at b64 bank floor
__device__ __forceinline__ int ZS(int i){ return i ^ ((i>>4)&15) ^ (((i>>8)&15)<<4); }

// ---- radix-4 butterflies (validated r1..r6 lineage) ----
__device__ __forceinline__ void r4_fwd(float2& x0, float2& x1, float2& x2, float2& x3,
                                       float2 w1, float2 w2, float2 w3) {
  float2 A = caddf(x0,x2), C = csubf(x0,x2);
  float2 B = caddf(x1,x3), D = csubf(x1,x3);
  float2 y1 = make_float2(C.x + D.y, C.y - D.x);   // C - iD
  float2 y3 = make_float2(C.x - D.y, C.y + D.x);   // C + iD
  x0 = caddf(A,B);
  x1 = cmulf(y1,w1);
  x2 = cmulf(csubf(A,B),w2);
  x3 = cmulf(y3,w3);
}
// inverse butterfly taking FORWARD twiddles (conj applied inside, free)
__device__ __forceinline__ void r4_invc(float2& y0, float2& y1, float2& y2, float2& y3,
                                        float2 w1, float2 w2, float2 w3) {
  float2 c1 = cmulc(y1,w1);
  float2 c2 = cmulc(y2,w2);
  float2 c3 = cmulc(y3,w3);
  float2 ap = caddf(y0,c2), bp = csubf(y0,c2);
  float2 cp = caddf(c1,c3);
  float2 dp = make_float2(c3.y - c1.y, c1.x - c3.x);  // i*(c1-c3)
  y0 = caddf(ap,cp); y1 = caddf(bp,dp); y2 = csubf(ap,cp); y3 = csubf(bp,dp);
}

#define DECL_CONSTS \
  const float C16R[4]={1.f,0.9238795325112867f,0.7071067811865476f,0.3826834323650898f}; \
  const float C16I[4]={0.f,-0.3826834323650898f,-0.7071067811865476f,-0.9238795325112867f}; \
  const float C8R[4] ={1.f,0.7071067811865476f,0.f,-0.7071067811865476f}; \
  const float C8I[4] ={0.f,-0.7071067811865476f,-1.f,-0.7071067811865476f}; \
  const float C163R[4]={1.f,0.3826834323650898f,-0.7071067811865476f,-0.9238795325112867f}; \
  const float C163I[4]={0.f,-0.9238795325112867f,-0.7071067811865476f,0.3826834323650898f};

__device__ __forceinline__ void r16_fwd1(float2 x[16]) {
  DECL_CONSTS
  #pragma unroll
  for (int k0 = 0; k0 < 4; k0++)
    r4_fwd(x[k0], x[k0+4], x[k0+8], x[k0+12],
           make_float2(C16R[k0],C16I[k0]), make_float2(C8R[k0],C8I[k0]),
           make_float2(C163R[k0],C163I[k0]));
  #pragma unroll
  for (int q = 0; q < 4; q++)
    r4_fwd(x[4*q], x[4*q+1], x[4*q+2], x[4*q+3],
           make_float2(1.f,0.f), make_float2(1.f,0.f), make_float2(1.f,0.f));
}
__device__ __forceinline__ void r16_inv1(float2 x[16]) {
  DECL_CONSTS
  #pragma unroll
  for (int q = 0; q < 4; q++)
    r4_invc(x[4*q], x[4*q+1], x[4*q+2], x[4*q+3],
            make_float2(1.f,0.f), make_float2(1.f,0.f), make_float2(1.f,0.f));
  #pragma unroll
  for (int k0 = 0; k0 < 4; k0++)
    r4_invc(x[k0], x[k0+4], x[k0+8], x[k0+12],
            make_float2(C16R[k0],C16I[k0]), make_float2(C8R[k0],C8I[k0]),
            make_float2(C163R[k0],C163I[k0]));
}
// table packs: w[0..3]=w1[k0], [4..7]=w2[k0], [8..11]=w3[k0], [12..14]=wB,wB2,wB3
__device__ __forceinline__ void r16_fwd_t(float2 x[16], const float4 tp[8]) {
  float2 tw[16];
  #pragma unroll
  for (int q = 0; q < 8; q++) {
    tw[2*q]   = make_float2(tp[q].x, tp[q].y);
    tw[2*q+1] = make_float2(tp[q].z, tp[q].w);
  }
  #pragma unroll
  for (int k0 = 0; k0 < 4; k0++)
    r4_fwd(x[k0], x[k0+4], x[k0+8], x[k0+12], tw[k0], tw[4+k0], tw[8+k0]);
  #pragma unroll
  for (int q = 0; q < 4; q++)
    r4_fwd(x[4*q], x[4*q+1], x[4*q+2], x[4*q+3], tw[12], tw[13], tw[14]);
}
__device__ __forceinline__ void r16_inv_t(float2 x[16], const float4 tp[8]) {
  float2 tw[16];
  #pragma unroll
  for (int q = 0; q < 8; q++) {
    tw[2*q]   = make_float2(tp[q].x, tp[q].y);
    tw[2*q+1] = make_float2(tp[q].z, tp[q].w);
  }
  #pragma unroll
  for (int q = 0; q < 4; q++)
    r4_invc(x[4*q], x[4*q+1], x[4*q+2], x[4*q+3], tw[12], tw[13], tw[14]);
  #pragma unroll
  for (int k0 = 0; k0 < 4; k0++)
    r4_invc(x[k0], x[k0+4], x[k0+8], x[k0+12], tw[k0], tw[4+k0], tw[8+k0]);
}

// ---------------- prep: twiddle-pack tables, one entry per thread ----------------
__device__ __forceinline__ double slotExpo(int s, int t) {   // 1/4096 units
  if (s < 4)  return (double)(t + 256*s);
  if (s < 8)  return (double)(2*t + 512*(s-4));
  if (s < 12) return (double)(3*t + 768*(s-8));
  if (s == 12) return (double)(4*t);
  if (s == 13) return (double)(8*t);
  if (s == 14) return (double)(12*t);
  return 0.0;
}
__device__ __forceinline__ float2 E4096(double e) {
  double ang = -2.0*M_PI*e/4096.0;
  return make_float2((float)cos(ang), (float)sin(ang));
}
__global__ void tables_kernel(float4* __restrict__ tp1, float4* __restrict__ tp2,
                              float2* __restrict__ wp3) {
  int idx = blockIdx.x*blockDim.x + threadIdx.x;
  if (idx < 2048) {                       // tp1[q*256+t], wA = W4096^t
    int q = idx >> 8, t = idx & 255;
    float2 wa = E4096(slotExpo(2*q,   t));
    float2 wb = E4096(slotExpo(2*q+1, t));
    tp1[q*256 + t] = make_float4(wa.x, wa.y, wb.x, wb.y);
  } else if (idx < 2176) {                // tp2[q*16+j], wA = W256^j = W4096^{16j}
    int r = idx - 2048; int q = r >> 4, j = r & 15;
    float2 wa = E4096(slotExpo(2*q,   16*j));
    float2 wb = E4096(slotExpo(2*q+1, 16*j));
    tp2[q*16 + j] = make_float4(wa.x, wa.y, wb.x, wb.y);
  } else if (idx < 2432) {                // wp3[b] = W8192^{RHO(b>>4)+16*RHO(b&15)}
    int b = idx - 2176;
    int e = RHO(b>>4) + 16*RHO(b&15);
    double ang = -2.0*M_PI*(double)e/8192.0;
    wp3[b] = make_float2((float)cos(ang), (float)sin(ang));
  }
}

// ---------------- prep: at_roots via 4 Cauchy dots (fp64) -- unchanged ----------------
__global__ void cauchy_kernel(const float* __restrict__ Lre, const float* __restrict__ Lim,
                              const float* __restrict__ Pre, const float* __restrict__ Pim,
                              const float* __restrict__ Bre, const float* __restrict__ Bim,
                              const float* __restrict__ Cri, const float* __restrict__ lstep,
                              float2* __restrict__ a_out) {
  int k = blockIdx.x*blockDim.x + threadIdx.x;
  if (k >= LSEQ) return;
  double step = exp((double)lstep[0]);
  double ang = -2.0*M_PI*(double)k/(double)LSEQ;
  double wr = cos(ang), wi = sin(ang);
  double nr = 1.0 - wr, ni = -wi;
  double dr = 1.0 + wr, di = wi;
  double dn = dr*dr + di*di;
  double gre = (2.0/step) * (nr*dr + ni*di)/dn;
  double gim = (2.0/step) * (ni*dr - nr*di)/dn;
  double cre = 2.0*dr/dn, cim = -2.0*di/dn;
  double k00r=0,k00i=0,k01r=0,k01i=0,k10r=0,k10i=0,k11r=0,k11i=0;
  for (int n = 0; n < NM; n++) {
    double lre = Lre[n], lim = Lim[n];
    double pre = Pre[n], pim = Pim[n];
    double bre = Bre[n], bim = Bim[n];
    double ccr = Cri[2*n], cci = Cri[2*n+1];
    double er = gre - lre, ei = gim - lim;
    double inv = 1.0/(er*er + ei*ei);
    double ir =  er*inv, ii = -ei*inv;
    double v00r = ccr*bre + cci*bim, v00i = ccr*bim - cci*bre;
    double v01r = ccr*pre + cci*pim, v01i = ccr*pim - cci*pre;
    double v10r = pre*bre + pim*bim, v10i = pre*bim - pim*bre;
    double v11r = pre*pre + pim*pim, v11i = 0.0;
    k00r += v00r*ir - v00i*ii;  k00i += v00r*ii + v00i*ir;
    k01r += v01r*ir - v01i*ii;  k01i += v01r*ii + v01i*ir;
    k10r += v10r*ir - v10i*ii;  k10i += v10r*ii + v10i*ir;
    k11r += v11r*ir - v11i*ii;  k11i += v11r*ii + v11i*ir;
  }
  double numr = k01r*k10r - k01i*k10i, numi = k01r*k10i + k01i*k10r;
  double der = 1.0 + k11r, dei = k11i;
  double dinv = 1.0/(der*der + dei*dei);
  double qr = (numr*der + numi*dei)*dinv;
  double qi = (numi*der - numr*dei)*dinv;
  double tr = k00r - qr, ti = k00i - qi;
  double ar = cre*tr - cim*ti, ai = cre*ti + cim*tr;
  a_out[k] = make_float2((float)ar, (float)ai);
}

// ---------------- prep: K[l] = Re(IDFT_L(a))[l], 64 lanes per output ----------------
__global__ void ktime_kernel(const float2* __restrict__ a, float* __restrict__ K) {
  int lane = threadIdx.x & 63;
  int l = blockIdx.x * (blockDim.x >> 6) + (threadIdx.x >> 6);
  if (l >= LSEQ) return;
  double ang0 = 2.0*M_PI*(double)((l*lane) & (LSEQ-1))/(double)LSEQ;
  double tr = cos(ang0), ti = sin(ang0);
  double ang1 = 2.0*M_PI*(double)(l & 63)/64.0;
  double wr = cos(ang1), wi = sin(ang1);
  double acc = 0.0;
  for (int k = 0; k < 64; k++) {
    float2 ak = a[lane + (k << 6)];
    acc += (double)ak.x*tr - (double)ak.y*ti;
    double ntr = tr*wr - ti*wi;
    ti = tr*wi + ti*wr;
    tr = ntr;
  }
  for (int off = 32; off > 0; off >>= 1) acc += __shfl_down(acc, off);
  if (lane == 0) K[l] = (float)(acc/(double)LSEQ);
}

// ---------------- prep: H[k] = sum_l K[l] W8192^{kl}, k=0..4096 (fp64 direct) ----------
__global__ void hspec_kernel(const float* __restrict__ K, float2* __restrict__ H) {
  int lane = threadIdx.x & 63;
  int k = blockIdx.x * (blockDim.x >> 6) + (threadIdx.x >> 6);
  if (k > NFFT) return;
  int m0 = (k*lane) & 8191;
  double a0 = -2.0*M_PI*(double)m0/8192.0;
  double cr = cos(a0), ci = sin(a0);
  int ms = (k << 6) & 8191;
  double as = -2.0*M_PI*(double)ms/8192.0;
  double sr = cos(as), si = sin(as);
  double accr = 0.0, acci = 0.0;
  for (int j = 0; j < 64; j++) {
    double Kv = (double)K[lane + (j << 6)];
    accr += Kv*cr; acci += Kv*ci;
    double nr2 = cr*sr - ci*si;
    ci = cr*si + ci*sr; cr = nr2;
  }
  for (int off = 32; off > 0; off >>= 1) {
    accr += __shfl_down(accr, off);
    acci += __shfl_down(acci, off);
  }
  if (lane == 0) H[k] = make_float2((float)accr, (float)acci);
}

// ---------------- prep: lay H out per (block,reg) with D folded and 1/16384 scale ------
__global__ void map_kernel(const float2* __restrict__ H, const float* __restrict__ Dp,
                           float2* __restrict__ KdA, float2* __restrict__ KdB) {
  int idx = blockIdx.x*blockDim.x + threadIdx.x;
  if (idx >= NFFT) return;
  int b = idx >> 4, c = idx & 15;
  int k = RHO(b>>4) + 16*RHO(b&15) + 256*RHO(c);
  const float s = 1.0f/16384.0f;
  float Dv = Dp[0];
  float2 ha = H[k], hb = H[NFFT - k];
  KdA[idx] = make_float2((ha.x + Dv)*s, ha.y*s);
  KdB[idx] = make_float2((hb.x + Dv)*s, hb.y*s);
}

// ---------------- main: 1 row/block, packed real-8192 FFT as complex-4096 ----------------
// 256 thr (4 waves), 32KB LDS. __launch_bounds__(256,2): empirical VGPR cap = 256/arg2
// on this toolchain ((512,4)->64, (256,4)->64, (512,2)->128); arg2=2 -> cap 128, which
// fits P3's x[16]+px[16]+kd[8] live set (~100 VGPR). arg2=4 spilled 1.18 GB to scratch.
__global__ __launch_bounds__(256, 2)
void conv_kernel(const float* __restrict__ u,
                 const float4* __restrict__ tp1, const float4* __restrict__ tp2,
                 const float2* __restrict__ wp3, const float2* __restrict__ KdA,
                 const float2* __restrict__ KdB, float* __restrict__ out) {
  __shared__ float2 z[NFFT];
  const int tid = threadIdx.x;
  const float2* u2 = (const float2*)(u + (size_t)blockIdx.x*LSEQ);
  float2 x[16];
  // ---- P1: load packed row, r16 fwd (stride 256) ----
  {
    float4 tpr[8];
    #pragma unroll
    for (int q = 0; q < 8; q++) tpr[q] = tp1[(q<<8) + tid];
    #pragma unroll
    for (int k = 0; k < 8; k++) x[k] = u2[tid + (k<<8)];
    #pragma unroll
    for (int k = 8; k < 16; k++) x[k] = make_float2(0.f, 0.f);
    r16_fwd_t(x, tpr);
    #pragma unroll
    for (int k = 0; k < 16; k++) z[ZS(tid + (k<<8))] = x[k];
  }
  __syncthreads();
  // ---- P2: r16 fwd (stride 16) ----
  const int j4 = tid & 15, gb = (tid>>4)<<8;
  {
    float4 tq[8];
    #pragma unroll
    for (int q = 0; q < 8; q++) tq[q] = tp2[(q<<4) + j4];
    #pragma unroll
    for (int k = 0; k < 16; k++) x[k] = z[ZS(gb + (k<<4) + j4)];
    r16_fwd_t(x, tq);
    #pragma unroll
    for (int k = 0; k < 16; k++) z[ZS(gb + (k<<4) + j4)] = x[k];
  }
  __syncthreads();
  // ---- P3: final r16 fwd + real-untangle x H + re-pack + r16 inv ----
  {
    // block assignment: group g handles high digit Hmap[g]; pairs co-wave
    int h16 = (int)((0xA9B8C7D6E5F42310ull >> ((tid>>4)<<2)) & 15);
    int b = (h16<<4) | j4;
    int pb;
    if (tid >= 16) pb = (RHO(16 - RHO(b>>4)) << 4) | (15 - j4);
    else           pb = (tid == 0) ? 0 : RHO(16 - RHO(tid));
    const int bb = b<<4, pbb = pb<<4;
    float2 px[16];
    #pragma unroll
    for (int c = 0; c < 16; c++) x[c] = z[ZS(bb + c)];
    #pragma unroll
    for (int c = 0; c < 16; c++) px[c] = z[ZS(pbb + c)];
    r16_fwd1(x);    // x[c]  = Z[k(b,c)],  k = RHO(b>>4)+16*RHO(b&15)+256*RHO(c)
    r16_fwd1(px);   // px[c] = Z[k(pb,c)]; mirror of x[c] is px[15-c] (thread0: M0T)
    const float2 wbase = wp3[b];
    const float4* KdA4 = (const float4*)(KdA + bb);
    const float4* KdB4 = (const float4*)(KdB + bb);
    // W32^{RHO(c)} = exp(-i*pi*RHO(c)/16)
    const float CW32R[16] = {1.f,0.7071067811865476f,0.f,-0.7071067811865476f,
                             0.9807852804032304f,0.5555702330196022f,-0.19509032201612825f,-0.8314696123025452f,
                             0.9238795325112867f,0.3826834323650898f,-0.3826834323650898f,-0.9238795325112867f,
                             0.8314696123025452f,0.19509032201612825f,-0.5555702330196022f,-0.9807852804032304f};
    const float CW32I[16] = {0.f,-0.7071067811865476f,-1.f,-0.7071067811865476f,
                             -0.19509032201612825f,-0.8314696123025452f,-0.9807852804032304f,-0.5555702330196022f,
                             -0.3826834323650898f,-0.9238795325112867f,-0.9238795325112867f,-0.3826834323650898f,
                             -0.5555702330196022f,-0.9807852804032304f,-0.8314696123025452f,-0.19509032201612825f};
    const int M0T[16] = {0,3,2,1,15,14,13,12,11,10,9,8,7,6,5,4};
    const bool t0 = (tid == 0);
    #pragma unroll
    for (int c2 = 0; c2 < 8; c2++) {
      float4 a4 = KdA4[c2], b4 = KdB4[c2];
      #pragma unroll
      for (int cc = 0; cc < 2; cc++) {
        const int c = 2*c2 + cc;
        float2 kda = cc ? make_float2(a4.z, a4.w) : make_float2(a4.x, a4.y);
        float2 kdb = cc ? make_float2(b4.z, b4.w) : make_float2(b4.x, b4.y);
        float2 Zo = x[c];
        float2 Zm = t0 ? px[M0T[c]] : px[15-c];
        float2 wk = cmulf(wbase, make_float2(CW32R[c], CW32I[c]));  // W8192^k
        float Sx = Zo.x + Zm.x, Sy = Zo.y - Zm.y;    // S = Zo + conj(Zm)
        float Dx = Zo.x - Zm.x, Dy = Zo.y + Zm.y;    // D = Zo - conj(Zm)
        float2 t1 = cmulf(wk, make_float2(Dx, Dy));
        float2 Up = make_float2(Sx + t1.y, Sy - t1.x);    // U'  = S - i*t1
        float2 Um = make_float2(Sx - t1.y, -Sy - t1.x);   // U'm = conj(S) - i*conj(t1)
        float2 Yp = cmulf(Up, kda);                        // ~ Y[k]
        float2 Ym = cmulf(Um, kdb);                        // ~ Y[N-k]
        float Pxx = Yp.x + Ym.x, Pyy = Yp.y - Ym.y;       // Y' + conj(Ym)
        float Qx  = Yp.x - Ym.x, Qy  = Yp.y + Ym.y;       // Y' - conj(Ym)
        float2 t2 = cmulc(make_float2(Qx, Qy), wk);        // Q * conj(wk)
        x[c] = make_float2(Pxx - t2.y, Pyy + t2.x);        // V = P + i*t2
      }
    }
    r16_inv1(x);
    #pragma unroll
    for (int c = 0; c < 16; c++) z[ZS(bb + c)] = x[c];
  }
  __syncthreads();
  // ---- P4: r16 inv (stride 16) ----
  {
    float4 tq[8];
    #pragma unroll
    for (int q = 0; q < 8; q++) tq[q] = tp2[(q<<4) + j4];
    #pragma unroll
    for (int k = 0; k < 16; k++) x[k] = z[ZS(gb + (k<<4) + j4)];
    r16_inv_t(x, tq);
    #pragma unroll
    for (int k = 0; k < 16; k++) z[ZS(gb + (k<<4) + j4)] = x[k];
  }
  __syncthreads();
  // ---- P5: r16 inv (stride 256), unpack v[n] = (y[2n], y[2n+1]) ----
  {
    float4 tpr[8];
    #pragma unroll
    for (int q = 0; q < 8; q++) tpr[q] = tp1[(q<<8) + tid];
    #pragma unroll
    for (int k = 0; k < 16; k++) x[k] = z[ZS(tid + (k<<8))];
    r16_inv_t(x, tpr);
    float2* o2 = (float2*)(out + (size_t)blockIdx.x*LSEQ);
    #pragma unroll
    for (int k = 0; k < 8; k++) o2[tid + (k<<8)] = x[k];
  }
}

extern "C" void kernel_launch(void* const* d_in, const int* in_sizes, int n_in,
                              void* d_out, int out_size, void* d_ws, size_t ws_size,
                              hipStream_t stream) {
  const float* u     = (const float*)d_in[0];
  const float* Lre   = (const float*)d_in[1];
  const float* Lim   = (const float*)d_in[2];
  const float* Pre   = (const float*)d_in[3];
  const float* Pim   = (const float*)d_in[4];
  const float* Bre   = (const float*)d_in[5];
  const float* Bim   = (const float*)d_in[6];
  const float* Cri   = (const float*)d_in[7];
  const float* Dp    = (const float*)d_in[8];
  const float* lstep = (const float*)d_in[9];
  float* out = (float*)d_out;

  char* ws = (char*)d_ws;
  float2* a_ws   = (float2*)(ws);             //  32768 B : at_roots
  float*  K_ws   = (float*)(ws + 32768);      //  16384 B : K time domain
  float4* tp1_ws = (float4*)(ws + 49152);     //  32768 B : P1/P5 packs [8][256]
  float4* tp2_ws = (float4*)(ws + 81920);     //   2048 B : P2/P4 packs [8][16]
  float2* wp3_ws = (float2*)(ws + 83968);     //   2048 B : per-block W8192 base
  float2* H_ws   = (float2*)(ws + 86016);     //  32776 B : half-spectrum H[0..4096]
  float2* KdA_ws = (float2*)(ws + 118800);    //  32768 B : H[k] per (block,reg)
  float2* KdB_ws = (float2*)(ws + 151568);    //  32768 B : H[N-k] per (block,reg)

  hipLaunchKernelGGL(tables_kernel, dim3(10),   dim3(256), 0, stream,
                     tp1_ws, tp2_ws, wp3_ws);
  hipLaunchKernelGGL(cauchy_kernel, dim3(64),   dim3(64),  0, stream,
                     Lre, Lim, Pre, Pim, Bre, Bim, Cri, lstep, a_ws);
  hipLaunchKernelGGL(ktime_kernel,  dim3(1024), dim3(256), 0, stream, a_ws, K_ws);
  hipLaunchKernelGGL(hspec_kernel,  dim3(1025), dim3(256), 0, stream, K_ws, H_ws);
  hipLaunchKernelGGL(map_kernel,    dim3(16),   dim3(256), 0, stream,
                     H_ws, Dp, KdA_ws, KdB_ws);
  hipLaunchKernelGGL(conv_kernel,   dim3(NBH),  dim3(256), 0, stream,
                     u, tp1_ws, tp2_ws, wp3_ws, KdA_ws, KdB_ws, out);
}

// Round 8
// 177.238 us; speedup vs baseline: 3.0915x; 1.3169x over previous
//
#include <hip/hip_runtime.h>
#include <math.h>

#define LSEQ 4096
#define NFFT 4096      // complex FFT length (real length 8192 via packing)
#define NM   64
#define NBH  4096

__device__ __forceinline__ float2 cmulf(float2 a, float2 b) {
  return make_float2(a.x*b.x - a.y*b.y, a.x*b.y + a.y*b.x);
}
// a * conj(b)
__device__ __forceinline__ float2 cmulc(float2 a, float2 b) {
  return make_float2(a.x*b.x + a.y*b.y, a.y*b.x - a.x*b.y);
}
__device__ __forceinline__ float2 caddf(float2 a, float2 b){ return make_float2(a.x+b.x, a.y+b.y); }
__device__ __forceinline__ float2 csubf(float2 a, float2 b){ return make_float2(a.x-b.x, a.y-b.y); }

// base-4 digit swap of a 4-bit value: reg r holds freq digit RHO(r) after fused r16
__host__ __device__ constexpr int RHO(int d){ return ((d&3)<<2) | (d>>2); }

// storage swizzle: phys[3:0]^=l[7:4], phys[7:4]^=l[11:8] -> all passes at b64 bank floor
__device__ __forceinline__ int ZS(int i){ return i ^ ((i>>4)&15) ^ (((i>>8)&15)<<4); }

// ---- radix-4 butterflies (validated r1..r7 lineage) ----
__device__ __forceinline__ void r4_fwd(float2& x0, float2& x1, float2& x2, float2& x3,
                                       float2 w1, float2 w2, float2 w3) {
  float2 A = caddf(x0,x2), C = csubf(x0,x2);
  float2 B = caddf(x1,x3), D = csubf(x1,x3);
  float2 y1 = make_float2(C.x + D.y, C.y - D.x);   // C - iD
  float2 y3 = make_float2(C.x - D.y, C.y + D.x);   // C + iD
  x0 = caddf(A,B);
  x1 = cmulf(y1,w1);
  x2 = cmulf(csubf(A,B),w2);
  x3 = cmulf(y3,w3);
}
// inverse butterfly taking FORWARD twiddles (conj applied inside, free)
__device__ __forceinline__ void r4_invc(float2& y0, float2& y1, float2& y2, float2& y3,
                                        float2 w1, float2 w2, float2 w3) {
  float2 c1 = cmulc(y1,w1);
  float2 c2 = cmulc(y2,w2);
  float2 c3 = cmulc(y3,w3);
  float2 ap = caddf(y0,c2), bp = csubf(y0,c2);
  float2 cp = caddf(c1,c3);
  float2 dp = make_float2(c3.y - c1.y, c1.x - c3.x);  // i*(c1-c3)
  y0 = caddf(ap,cp); y1 = caddf(bp,dp); y2 = csubf(ap,cp); y3 = csubf(bp,dp);
}

#define DECL_CONSTS \
  const float C16R[4]={1.f,0.9238795325112867f,0.7071067811865476f,0.3826834323650898f}; \
  const float C16I[4]={0.f,-0.3826834323650898f,-0.7071067811865476f,-0.9238795325112867f}; \
  const float C8R[4] ={1.f,0.7071067811865476f,0.f,-0.7071067811865476f}; \
  const float C8I[4] ={0.f,-0.7071067811865476f,-1.f,-0.7071067811865476f}; \
  const float C163R[4]={1.f,0.3826834323650898f,-0.7071067811865476f,-0.9238795325112867f}; \
  const float C163I[4]={0.f,-0.9238795325112867f,-0.7071067811865476f,0.3826834323650898f};

__device__ __forceinline__ void r16_fwd1(float2 x[16]) {
  DECL_CONSTS
  #pragma unroll
  for (int k0 = 0; k0 < 4; k0++)
    r4_fwd(x[k0], x[k0+4], x[k0+8], x[k0+12],
           make_float2(C16R[k0],C16I[k0]), make_float2(C8R[k0],C8I[k0]),
           make_float2(C163R[k0],C163I[k0]));
  #pragma unroll
  for (int q = 0; q < 4; q++)
    r4_fwd(x[4*q], x[4*q+1], x[4*q+2], x[4*q+3],
           make_float2(1.f,0.f), make_float2(1.f,0.f), make_float2(1.f,0.f));
}
__device__ __forceinline__ void r16_inv1(float2 x[16]) {
  DECL_CONSTS
  #pragma unroll
  for (int q = 0; q < 4; q++)
    r4_invc(x[4*q], x[4*q+1], x[4*q+2], x[4*q+3],
            make_float2(1.f,0.f), make_float2(1.f,0.f), make_float2(1.f,0.f));
  #pragma unroll
  for (int k0 = 0; k0 < 4; k0++)
    r4_invc(x[k0], x[k0+4], x[k0+8], x[k0+12],
            make_float2(C16R[k0],C16I[k0]), make_float2(C8R[k0],C8I[k0]),
            make_float2(C163R[k0],C163I[k0]));
}
// table packs: w[0..3]=w1[k0], [4..7]=w2[k0], [8..11]=w3[k0], [12..14]=wB,wB2,wB3
__device__ __forceinline__ void r16_fwd_t(float2 x[16], const float4 tp[8]) {
  float2 tw[16];
  #pragma unroll
  for (int q = 0; q < 8; q++) {
    tw[2*q]   = make_float2(tp[q].x, tp[q].y);
    tw[2*q+1] = make_float2(tp[q].z, tp[q].w);
  }
  #pragma unroll
  for (int k0 = 0; k0 < 4; k0++)
    r4_fwd(x[k0], x[k0+4], x[k0+8], x[k0+12], tw[k0], tw[4+k0], tw[8+k0]);
  #pragma unroll
  for (int q = 0; q < 4; q++)
    r4_fwd(x[4*q], x[4*q+1], x[4*q+2], x[4*q+3], tw[12], tw[13], tw[14]);
}
__device__ __forceinline__ void r16_inv_t(float2 x[16], const float4 tp[8]) {
  float2 tw[16];
  #pragma unroll
  for (int q = 0; q < 8; q++) {
    tw[2*q]   = make_float2(tp[q].x, tp[q].y);
    tw[2*q+1] = make_float2(tp[q].z, tp[q].w);
  }
  #pragma unroll
  for (int q = 0; q < 4; q++)
    r4_invc(x[4*q], x[4*q+1], x[4*q+2], x[4*q+3], tw[12], tw[13], tw[14]);
  #pragma unroll
  for (int k0 = 0; k0 < 4; k0++)
    r4_invc(x[k0], x[k0+4], x[k0+8], x[k0+12], tw[k0], tw[4+k0], tw[8+k0]);
}

// ---------------- prep: twiddle-pack tables, one entry per thread ----------------
__device__ __forceinline__ double slotExpo(int s, int t) {   // 1/4096 units
  if (s < 4)  return (double)(t + 256*s);
  if (s < 8)  return (double)(2*t + 512*(s-4));
  if (s < 12) return (double)(3*t + 768*(s-8));
  if (s == 12) return (double)(4*t);
  if (s == 13) return (double)(8*t);
  if (s == 14) return (double)(12*t);
  return 0.0;
}
__device__ __forceinline__ float2 E4096(double e) {
  double ang = -2.0*M_PI*e/4096.0;
  return make_float2((float)cos(ang), (float)sin(ang));
}
__global__ void tables_kernel(float4* __restrict__ tp1, float4* __restrict__ tp2,
                              float2* __restrict__ wp3) {
  int idx = blockIdx.x*blockDim.x + threadIdx.x;
  if (idx < 2048) {                       // tp1[q*256+t], wA = W4096^t
    int q = idx >> 8, t = idx & 255;
    float2 wa = E4096(slotExpo(2*q,   t));
    float2 wb = E4096(slotExpo(2*q+1, t));
    tp1[q*256 + t] = make_float4(wa.x, wa.y, wb.x, wb.y);
  } else if (idx < 2176) {                // tp2[q*16+j], wA = W256^j = W4096^{16j}
    int r = idx - 2048; int q = r >> 4, j = r & 15;
    float2 wa = E4096(slotExpo(2*q,   16*j));
    float2 wb = E4096(slotExpo(2*q+1, 16*j));
    tp2[q*16 + j] = make_float4(wa.x, wa.y, wb.x, wb.y);
  } else if (idx < 2432) {                // wp3[b] = W8192^{RHO(b>>4)+16*RHO(b&15)}
    int b = idx - 2176;
    int e = RHO(b>>4) + 16*RHO(b&15);
    double ang = -2.0*M_PI*(double)e/8192.0;
    wp3[b] = make_float2((float)cos(ang), (float)sin(ang));
  }
}

// ---------------- prep: at_roots via 4 Cauchy dots (fp64) -- unchanged ----------------
__global__ void cauchy_kernel(const float* __restrict__ Lre, const float* __restrict__ Lim,
                              const float* __restrict__ Pre, const float* __restrict__ Pim,
                              const float* __restrict__ Bre, const float* __restrict__ Bim,
                              const float* __restrict__ Cri, const float* __restrict__ lstep,
                              float2* __restrict__ a_out) {
  int k = blockIdx.x*blockDim.x + threadIdx.x;
  if (k >= LSEQ) return;
  double step = exp((double)lstep[0]);
  double ang = -2.0*M_PI*(double)k/(double)LSEQ;
  double wr = cos(ang), wi = sin(ang);
  double nr = 1.0 - wr, ni = -wi;
  double dr = 1.0 + wr, di = wi;
  double dn = dr*dr + di*di;
  double gre = (2.0/step) * (nr*dr + ni*di)/dn;
  double gim = (2.0/step) * (ni*dr - nr*di)/dn;
  double cre = 2.0*dr/dn, cim = -2.0*di/dn;
  double k00r=0,k00i=0,k01r=0,k01i=0,k10r=0,k10i=0,k11r=0,k11i=0;
  for (int n = 0; n < NM; n++) {
    double lre = Lre[n], lim = Lim[n];
    double pre = Pre[n], pim = Pim[n];
    double bre = Bre[n], bim = Bim[n];
    double ccr = Cri[2*n], cci = Cri[2*n+1];
    double er = gre - lre, ei = gim - lim;
    double inv = 1.0/(er*er + ei*ei);
    double ir =  er*inv, ii = -ei*inv;
    double v00r = ccr*bre + cci*bim, v00i = ccr*bim - cci*bre;
    double v01r = ccr*pre + cci*pim, v01i = ccr*pim - cci*pre;
    double v10r = pre*bre + pim*bim, v10i = pre*bim - pim*bre;
    double v11r = pre*pre + pim*pim, v11i = 0.0;
    k00r += v00r*ir - v00i*ii;  k00i += v00r*ii + v00i*ir;
    k01r += v01r*ir - v01i*ii;  k01i += v01r*ii + v01i*ir;
    k10r += v10r*ir - v10i*ii;  k10i += v10r*ii + v10i*ir;
    k11r += v11r*ir - v11i*ii;  k11i += v11r*ii + v11i*ir;
  }
  double numr = k01r*k10r - k01i*k10i, numi = k01r*k10i + k01i*k10r;
  double der = 1.0 + k11r, dei = k11i;
  double dinv = 1.0/(der*der + dei*dei);
  double qr = (numr*der + numi*dei)*dinv;
  double qi = (numi*der - numr*dei)*dinv;
  double tr = k00r - qr, ti = k00i - qi;
  double ar = cre*tr - cim*ti, ai = cre*ti + cim*tr;
  a_out[k] = make_float2((float)ar, (float)ai);
}

// ---------------- prep: K[l] = Re(IDFT_L(a))[l], 64 lanes per output ----------------
__global__ void ktime_kernel(const float2* __restrict__ a, float* __restrict__ K) {
  int lane = threadIdx.x & 63;
  int l = blockIdx.x * (blockDim.x >> 6) + (threadIdx.x >> 6);
  if (l >= LSEQ) return;
  double ang0 = 2.0*M_PI*(double)((l*lane) & (LSEQ-1))/(double)LSEQ;
  double tr = cos(ang0), ti = sin(ang0);
  double ang1 = 2.0*M_PI*(double)(l & 63)/64.0;
  double wr = cos(ang1), wi = sin(ang1);
  double acc = 0.0;
  for (int k = 0; k < 64; k++) {
    float2 ak = a[lane + (k << 6)];
    acc += (double)ak.x*tr - (double)ak.y*ti;
    double ntr = tr*wr - ti*wi;
    ti = tr*wi + ti*wr;
    tr = ntr;
  }
  for (int off = 32; off > 0; off >>= 1) acc += __shfl_down(acc, off);
  if (lane == 0) K[l] = (float)(acc/(double)LSEQ);
}

// ---------------- prep: H[k] = sum_l K[l] W8192^{kl}, k=0..4096 (fp64 direct) ----------
__global__ void hspec_kernel(const float* __restrict__ K, float2* __restrict__ H) {
  int lane = threadIdx.x & 63;
  int k = blockIdx.x * (blockDim.x >> 6) + (threadIdx.x >> 6);
  if (k > NFFT) return;
  int m0 = (k*lane) & 8191;
  double a0 = -2.0*M_PI*(double)m0/8192.0;
  double cr = cos(a0), ci = sin(a0);
  int ms = (k << 6) & 8191;
  double as = -2.0*M_PI*(double)ms/8192.0;
  double sr = cos(as), si = sin(as);
  double accr = 0.0, acci = 0.0;
  for (int j = 0; j < 64; j++) {
    double Kv = (double)K[lane + (j << 6)];
    accr += Kv*cr; acci += Kv*ci;
    double nr2 = cr*sr - ci*si;
    ci = cr*si + ci*sr; cr = nr2;
  }
  for (int off = 32; off > 0; off >>= 1) {
    accr += __shfl_down(accr, off);
    acci += __shfl_down(acci, off);
  }
  if (lane == 0) H[k] = make_float2((float)accr, (float)acci);
}

// ---------------- prep: lay H out per (block,reg) with D folded and 1/16384 scale ------
__global__ void map_kernel(const float2* __restrict__ H, const float* __restrict__ Dp,
                           float2* __restrict__ KdA, float2* __restrict__ KdB) {
  int idx = blockIdx.x*blockDim.x + threadIdx.x;
  if (idx >= NFFT) return;
  int b = idx >> 4, c = idx & 15;
  int k = RHO(b>>4) + 16*RHO(b&15) + 256*RHO(c);
  const float s = 1.0f/16384.0f;
  float Dv = Dp[0];
  float2 ha = H[k], hb = H[NFFT - k];
  KdA[idx] = make_float2((ha.x + Dv)*s, ha.y*s);
  KdB[idx] = make_float2((hb.x + Dv)*s, hb.y*s);
}

// ---------------- main: 1 row/block, packed real-8192 FFT as complex-4096 ----------------
// 256 thr (4 waves), 32KB LDS, (256,2) -> VGPR cap 128. P3 is SPLIT into
// publish(P3a)/spectral-read(P3b)/inverse(P3c) phases so the partner spectrum is read
// from LDS one value at a time instead of held as px[16] in regs -- r7 showed the
// px-resident version needs >128 live VGPRs and spilled ~330MB to scratch.
__global__ __launch_bounds__(256, 2)
void conv_kernel(const float* __restrict__ u,
                 const float4* __restrict__ tp1, const float4* __restrict__ tp2,
                 const float2* __restrict__ wp3, const float2* __restrict__ KdA,
                 const float2* __restrict__ KdB, float* __restrict__ out) {
  __shared__ float2 z[NFFT];
  const int tid = threadIdx.x;
  const float2* u2 = (const float2*)(u + (size_t)blockIdx.x*LSEQ);
  float2 x[16];
  // ---- P1: load packed row, r16 fwd (stride 256) ----
  {
    float4 tpr[8];
    #pragma unroll
    for (int q = 0; q < 8; q++) tpr[q] = tp1[(q<<8) + tid];
    #pragma unroll
    for (int k = 0; k < 8; k++) x[k] = u2[tid + (k<<8)];
    #pragma unroll
    for (int k = 8; k < 16; k++) x[k] = make_float2(0.f, 0.f);
    r16_fwd_t(x, tpr);
    #pragma unroll
    for (int k = 0; k < 16; k++) z[ZS(tid + (k<<8))] = x[k];
  }
  __syncthreads();
  // ---- P2: r16 fwd (stride 16) ----
  const int j4 = tid & 15, gb = (tid>>4)<<8;
  {
    float4 tq[8];
    #pragma unroll
    for (int q = 0; q < 8; q++) tq[q] = tp2[(q<<4) + j4];
    #pragma unroll
    for (int k = 0; k < 16; k++) x[k] = z[ZS(gb + (k<<4) + j4)];
    r16_fwd_t(x, tq);
    #pragma unroll
    for (int k = 0; k < 16; k++) z[ZS(gb + (k<<4) + j4)] = x[k];
  }
  __syncthreads();
  // ---- P3a: final r16 fwd, publish spectrum to LDS (x stays in regs) ----
  // block assignment: group g handles high digit Hmap[g]; pairs co-wave
  const int h16 = (int)((0xA9B8C7D6E5F42310ull >> ((tid>>4)<<2)) & 15);
  const int b = (h16<<4) | j4;
  int pb;
  if (tid >= 16) pb = (RHO(16 - RHO(b>>4)) << 4) | (15 - j4);
  else           pb = (tid == 0) ? 0 : RHO(16 - RHO(tid));
  const int bb = b<<4, pbb = pb<<4;
  {
    #pragma unroll
    for (int c = 0; c < 16; c++) x[c] = z[ZS(bb + c)];
    r16_fwd1(x);    // x[c] = Z[k(b,c)], k = RHO(b>>4)+16*RHO(b&15)+256*RHO(c)
    #pragma unroll
    for (int c = 0; c < 16; c++) z[ZS(bb + c)] = x[c];
  }
  __syncthreads();
  // ---- P3b: spectral op; z is READ-ONLY here (mirrors read one at a time) ----
  {
    const float2 wbase = wp3[b];
    const float4* KdA4 = (const float4*)(KdA + bb);
    const float4* KdB4 = (const float4*)(KdB + bb);
    // W32^{RHO(c)} = exp(-i*pi*RHO(c)/16)
    const float CW32R[16] = {1.f,0.7071067811865476f,0.f,-0.7071067811865476f,
                             0.9807852804032304f,0.5555702330196022f,-0.19509032201612825f,-0.8314696123025452f,
                             0.9238795325112867f,0.3826834323650898f,-0.3826834323650898f,-0.9238795325112867f,
                             0.8314696123025452f,0.19509032201612825f,-0.5555702330196022f,-0.9807852804032304f};
    const float CW32I[16] = {0.f,-0.7071067811865476f,-1.f,-0.7071067811865476f,
                             -0.19509032201612825f,-0.8314696123025452f,-0.9807852804032304f,-0.5555702330196022f,
                             -0.3826834323650898f,-0.9238795325112867f,-0.9238795325112867f,-0.3826834323650898f,
                             -0.5555702330196022f,-0.9807852804032304f,-0.8314696123025452f,-0.19509032201612825f};
    const int M0T[16] = {0,3,2,1,15,14,13,12,11,10,9,8,7,6,5,4};
    const bool t0 = (tid == 0);
    #pragma unroll
    for (int c2 = 0; c2 < 8; c2++) {
      float4 a4 = KdA4[c2], b4 = KdB4[c2];
      #pragma unroll
      for (int cc = 0; cc < 2; cc++) {
        const int c = 2*c2 + cc;
        float2 kda = cc ? make_float2(a4.z, a4.w) : make_float2(a4.x, a4.y);
        float2 kdb = cc ? make_float2(b4.z, b4.w) : make_float2(b4.x, b4.y);
        const int mc = t0 ? M0T[c] : (15 - c);
        float2 Zo = x[c];
        float2 Zm = z[ZS(pbb + mc)];
        float2 wk = cmulf(wbase, make_float2(CW32R[c], CW32I[c]));  // W8192^k
        float Sx = Zo.x + Zm.x, Sy = Zo.y - Zm.y;    // S = Zo + conj(Zm)
        float Dx = Zo.x - Zm.x, Dy = Zo.y + Zm.y;    // D = Zo - conj(Zm)
        float2 t1 = cmulf(wk, make_float2(Dx, Dy));
        float2 Up = make_float2(Sx + t1.y, Sy - t1.x);    // U'  = S - i*t1
        float2 Um = make_float2(Sx - t1.y, -Sy - t1.x);   // U'm = conj(S) - i*conj(t1)
        float2 Yp = cmulf(Up, kda);                        // ~ Y[k]
        float2 Ym = cmulf(Um, kdb);                        // ~ Y[N-k]
        float Pxx = Yp.x + Ym.x, Pyy = Yp.y - Ym.y;       // Y' + conj(Ym)
        float Qx  = Yp.x - Ym.x, Qy  = Yp.y + Ym.y;       // Y' - conj(Ym)
        float2 t2 = cmulc(make_float2(Qx, Qy), wk);        // Q * conj(wk)
        x[c] = make_float2(Pxx - t2.y, Pyy + t2.x);        // V = P + i*t2
      }
    }
  }
  __syncthreads();
  // ---- P3c: r16 inv (const twiddles), write back ----
  {
    r16_inv1(x);
    #pragma unroll
    for (int c = 0; c < 16; c++) z[ZS(bb + c)] = x[c];
  }
  __syncthreads();
  // ---- P4: r16 inv (stride 16) ----
  {
    float4 tq[8];
    #pragma unroll
    for (int q = 0; q < 8; q++) tq[q] = tp2[(q<<4) + j4];
    #pragma unroll
    for (int k = 0; k < 16; k++) x[k] = z[ZS(gb + (k<<4) + j4)];
    r16_inv_t(x, tq);
    #pragma unroll
    for (int k = 0; k < 16; k++) z[ZS(gb + (k<<4) + j4)] = x[k];
  }
  __syncthreads();
  // ---- P5: r16 inv (stride 256), unpack v[n] = (y[2n], y[2n+1]) ----
  {
    float4 tpr[8];
    #pragma unroll
    for (int q = 0; q < 8; q++) tpr[q] = tp1[(q<<8) + tid];
    #pragma unroll
    for (int k = 0; k < 16; k++) x[k] = z[ZS(tid + (k<<8))];
    r16_inv_t(x, tpr);
    float2* o2 = (float2*)(out + (size_t)blockIdx.x*LSEQ);
    #pragma unroll
    for (int k = 0; k < 8; k++) o2[tid + (k<<8)] = x[k];
  }
}

extern "C" void kernel_launch(void* const* d_in, const int* in_sizes, int n_in,
                              void* d_out, int out_size, void* d_ws, size_t ws_size,
                              hipStream_t stream) {
  const float* u     = (const float*)d_in[0];
  const float* Lre   = (const float*)d_in[1];
  const float* Lim   = (const float*)d_in[2];
  const float* Pre   = (const float*)d_in[3];
  const float* Pim   = (const float*)d_in[4];
  const float* Bre   = (const float*)d_in[5];
  const float* Bim   = (const float*)d_in[6];
  const float* Cri   = (const float*)d_in[7];
  const float* Dp    = (const float*)d_in[8];
  const float* lstep = (const float*)d_in[9];
  float* out = (float*)d_out;

  char* ws = (char*)d_ws;
  float2* a_ws   = (float2*)(ws);             //  32768 B : at_roots
  float*  K_ws   = (float*)(ws + 32768);      //  16384 B : K time domain
  float4* tp1_ws = (float4*)(ws + 49152);     //  32768 B : P1/P5 packs [8][256]
  float4* tp2_ws = (float4*)(ws + 81920);     //   2048 B : P2/P4 packs [8][16]
  float2* wp3_ws = (float2*)(ws + 83968);     //   2048 B : per-block W8192 base
  float2* H_ws   = (float2*)(ws + 86016);     //  32776 B : half-spectrum H[0..4096]
  float2* KdA_ws = (float2*)(ws + 118800);    //  32768 B : H[k] per (block,reg)
  float2* KdB_ws = (float2*)(ws + 151568);    //  32768 B : H[N-k] per (block,reg)

  hipLaunchKernelGGL(tables_kernel, dim3(10),   dim3(256), 0, stream,
                     tp1_ws, tp2_ws, wp3_ws);
  hipLaunchKernelGGL(cauchy_kernel, dim3(64),   dim3(64),  0, stream,
                     Lre, Lim, Pre, Pim, Bre, Bim, Cri, lstep, a_ws);
  hipLaunchKernelGGL(ktime_kernel,  dim3(1024), dim3(256), 0, stream, a_ws, K_ws);
  hipLaunchKernelGGL(hspec_kernel,  dim3(1025), dim3(256), 0, stream, K_ws, H_ws);
  hipLaunchKernelGGL(map_kernel,    dim3(16),   dim3(256), 0, stream,
                     H_ws, Dp, KdA_ws, KdB_ws);
  hipLaunchKernelGGL(conv_kernel,   dim3(NBH),  dim3(256), 0, stream,
                     u, tp1_ws, tp2_ws, wp3_ws, KdA_ws, KdB_ws, out);
}